// Round 1
// 1337.952 us; speedup vs baseline: 1.0936x; 1.0936x over previous
//
#include <hip/hip_runtime.h>
#include <stdint.h>

// Problem constants
#define BTOT     65536
#define IN_DIM   1024
#define NUM_PROD 2048
#define OUT_DIM  2048

// GEMM geometry: 256x256 tile, BK=64, 8 waves (2M x 4N), 8-phase schedule
#define BK        64
#define NT        (NUM_PROD / BK)   // 32 K-tiles
#define BUF_ELEMS (256 * BK)        // one matrix buffer: 256 rows x 64 u16

typedef unsigned short u16;
typedef __attribute__((ext_vector_type(8))) short          bf16x8;
typedef __attribute__((ext_vector_type(8))) unsigned short ushort8;
typedef __attribute__((ext_vector_type(4))) float          f32x4;

// round-to-nearest-even fp32 -> bf16 (bit pattern)
__device__ __forceinline__ u16 f2bf(float f) {
    uint32_t u = __float_as_uint(f);
    u = (u + 0x7fff + ((u >> 16) & 1)) >> 16;
    return (u16)u;
}

// async global->LDS, 16B per lane; LDS dest = wave-uniform base + lane*16
__device__ __forceinline__ void load_lds16(const void* g, void* l) {
    __builtin_amdgcn_global_load_lds((const __attribute__((address_space(1))) void*)g,
                                     (__attribute__((address_space(3))) void*)l,
                                     16, 0, 0);
}

#define WAITV(n)                                                    \
    {                                                               \
        asm volatile("s_waitcnt vmcnt(" #n ")" ::: "memory");       \
        __builtin_amdgcn_sched_barrier(0);                          \
    }
#define FENCE() asm volatile("" ::: "memory")

// ---------------------------------------------------------------------------
// Kernel 1: W_prod (fp32 [OUT_DIM][NUM_PROD]) -> bf16 bits
// ---------------------------------------------------------------------------
__global__ __launch_bounds__(256) void cast_w_kernel(const float* __restrict__ W,
                                                     u16* __restrict__ Wb) {
    int i = blockIdx.x * 256 + threadIdx.x;          // group of 8 floats
    const float4* wp = (const float4*)W;
    float4 a = wp[2 * i];
    float4 b = wp[2 * i + 1];
    ushort8 o;
    o[0] = f2bf(a.x); o[1] = f2bf(a.y); o[2] = f2bf(a.z); o[3] = f2bf(a.w);
    o[4] = f2bf(b.x); o[5] = f2bf(b.y); o[6] = f2bf(b.z); o[7] = f2bf(b.w);
    *(ushort8*)(Wb + (size_t)i * 8) = o;
}

// ---------------------------------------------------------------------------
// Kernel 2: Q[b][p] = bf16( x[b][i_p] * x[b][j_p] )
// One row PER WAVE, zero barriers (wave-private LDS slot, own vmcnt),
// double-buffered row staging via global_load_lds; pairs in registers.
// ---------------------------------------------------------------------------
__global__ __launch_bounds__(256) void quad_kernel(const float* __restrict__ x,
                                                   const int*   __restrict__ idx,
                                                   u16*         __restrict__ Q,
                                                   int rowBase, int rowsChunk) {
    __shared__ float xs[8][IN_DIM];          // 4 waves * 2 slots * 4KB = 32KB
    const int lane = threadIdx.x & 63;
    const int wave = threadIdx.x >> 6;
    const int gw   = blockIdx.x * 4 + wave;  // global wave id
    const int NW   = gridDim.x * 4;

    // 32 pairs/lane, held in registers across all rows
    int2 pr[32];
    const int2* ip = (const int2*)idx;
#pragma unroll
    for (int c = 0; c < 4; ++c)
#pragma unroll
        for (int k = 0; k < 8; ++k)
            pr[c * 8 + k] = ip[(c * 64 + lane) * 8 + k];

    if (gw >= rowsChunk) return;

    // prologue: stage first row into slot 0 (4 x 1KB wave loads = 4KB row)
    {
        const float* xr = x + (size_t)(rowBase + gw) * IN_DIM;
        float* slot = xs[wave * 2];
#pragma unroll
        for (int i = 0; i < 4; ++i)
            load_lds16(xr + i * 256 + lane * 4, slot + i * 256);
    }

    int it = 0;
    for (int r = gw; r < rowsChunk; r += NW, ++it) {
        const int rn = r + NW;
        const bool nxt = (rn < rowsChunk);
        if (nxt) {   // stage next row into the other slot (in flight over compute)
            const float* xr = x + (size_t)(rowBase + rn) * IN_DIM;
            float* slot = xs[wave * 2 + ((it + 1) & 1)];
#pragma unroll
            for (int i = 0; i < 4; ++i)
                load_lds16(xr + i * 256 + lane * 4, slot + i * 256);
        }
        // per-wave vmcnt ledger (loads AND stores count):
        //   steady:  [cur stage 4][prev stores 4][next stage 4] -> wait to 8
        //   first:   [cur stage 4][next stage 4]                -> wait to 4
        //   last:    [cur stage 4][prev stores 4]               -> wait to 4
        //   single:  [cur stage 4]                              -> wait to 0
        if (nxt) { if (it) { WAITV(8); } else { WAITV(4); } }
        else     { if (it) { WAITV(4); } else { WAITV(0); } }

        const float* xr = xs[wave * 2 + (it & 1)];
        u16* qp = Q + (size_t)r * NUM_PROD;
#pragma unroll
        for (int c = 0; c < 4; ++c) {
            ushort8 o;
#pragma unroll
            for (int k = 0; k < 8; ++k) {
                const int2 p = pr[c * 8 + k];
                o[k] = f2bf(xr[p.x] * xr[p.y]);
            }
            *(ushort8*)(qp + (size_t)(c * 64 + lane) * 8) = o;   // coalesced 1KB/wave
        }
    }
}

// ---------------------------------------------------------------------------
// Kernel 3: 256x256x(K=2048) bf16 GEMM, 8-phase schedule (T1+T3+T4+T5).
//   - 2 LDS K-tile buffers (A+B each 32KB) = 128KB, BK=64
//   - phase = one C-quadrant (rh,ch): touches only A-half rh / B-half ch
//   - half-granular ring staging: p1->B1(t+1) p2->A1(t+1) p3->A0(t+2) p4->B0(t+2)
//   - boundary vmcnt(4): 2 half-tiles (4 loads) stay in flight across barriers
//   - chunk-XOR LDS swizzle (proven conflict-free), setprio around MFMA cluster
// ---------------------------------------------------------------------------
__device__ __forceinline__ void stage_half(const u16* __restrict__ g, u16* l) {
    // 128 rows x 64 cols u16 = 16KB = 512 threads x 2 x 16B
    const int lane = threadIdx.x & 63;
    const int wave = threadIdx.x >> 6;
#pragma unroll
    for (int i = 0; i < 2; ++i) {
        const int chunkBase = i * 512 + wave * 64;   // wave-uniform
        const int physChunk = chunkBase + lane;
        const int physRow   = physChunk >> 3;
        const int physCol   = physChunk & 7;
        const int srcChunk  = physCol ^ (physRow & 7);   // pre-swizzled source
        load_lds16(g + (size_t)physRow * NUM_PROD + srcChunk * 8,
                   l + chunkBase * 8);
    }
}

#define PHASE(RH, CH, STAGE_STMT, TAIL_STMT)                                        \
  {                                                                                 \
    bf16x8 af[2][4];                                                                \
    bf16x8 bfr[2][2];                                                               \
    _Pragma("unroll")                                                               \
    for (int ks = 0; ks < 2; ++ks) {                                                \
      _Pragma("unroll")                                                             \
      for (int mt = 0; mt < 4; ++mt) {                                              \
        const int rra = (RH) * 128 + wrow + mt * 16 + lr;                           \
        af[ks][mt] = *(const bf16x8*)&As_t[rra * BK + (((ks * 4 + q) ^ (lr & 7)) * 8)]; \
      }                                                                             \
      _Pragma("unroll")                                                             \
      for (int nt = 0; nt < 2; ++nt) {                                              \
        const int rrb = (CH) * 128 + wcol + nt * 16 + lr;                           \
        bfr[ks][nt] = *(const bf16x8*)&Bs_t[rrb * BK + (((ks * 4 + q) ^ (lr & 7)) * 8)]; \
      }                                                                             \
    }                                                                               \
    STAGE_STMT;                                                                     \
    FENCE();                                                                        \
    __builtin_amdgcn_s_barrier();                                                   \
    asm volatile("s_waitcnt lgkmcnt(0)" ::: "memory");                              \
    __builtin_amdgcn_sched_barrier(0);                                              \
    __builtin_amdgcn_s_setprio(1);                                                  \
    _Pragma("unroll")                                                               \
    for (int ks = 0; ks < 2; ++ks)                                                  \
      _Pragma("unroll")                                                             \
      for (int mt = 0; mt < 4; ++mt)                                                \
        _Pragma("unroll")                                                           \
        for (int nt = 0; nt < 2; ++nt)                                              \
          acc[RH][CH][mt][nt] = __builtin_amdgcn_mfma_f32_16x16x32_bf16(            \
              af[ks][mt], bfr[ks][nt], acc[RH][CH][mt][nt], 0, 0, 0);               \
    __builtin_amdgcn_s_setprio(0);                                                  \
    TAIL_STMT;                                                                      \
    FENCE();                                                                        \
    __builtin_amdgcn_s_barrier();                                                   \
  }

__global__ __launch_bounds__(512, 2) void gemm256(const u16* __restrict__ A,
                                                  const u16* __restrict__ Bm,
                                                  float*     __restrict__ C) {
    __shared__ __align__(16) u16 As[2 * BUF_ELEMS];   // 64KB
    __shared__ __align__(16) u16 Bs[2 * BUF_ELEMS];   // 64KB

    const int tid  = threadIdx.x;
    const int lane = tid & 63;
    const int wave = tid >> 6;
    const int q    = lane >> 4;
    const int lr   = lane & 15;
    const int wrow = (wave >> 2) * 64;   // wave row offset inside a 128-row half
    const int wcol = (wave & 3) * 32;    // wave col offset inside a 128-col half

    // XCD-aware swizzle (nwg = 8 * rows/256, always % 8 == 0 -> bijective)
    const int nwg = gridDim.x * gridDim.y;
    const int bid = blockIdx.y * gridDim.x + blockIdx.x;
    const int cpx = nwg >> 3;
    const int swz = (bid & 7) * cpx + (bid >> 3);
    const int bx  = swz & 7;     // gridDim.x == 8
    const int by  = swz >> 3;

    const u16* Ag = A  + (size_t)by * 256 * NUM_PROD;
    const u16* Bg = Bm + (size_t)bx * 256 * NUM_PROD;

    f32x4 acc[2][2][4][2] = {};

    // prologue: tile0 fully + A0,B0 of tile1 (steady-state carry-in)
    stage_half(Ag,                           As);                 // A0(0)
    stage_half(Bg,                           Bs);                 // B0(0)
    stage_half(Bg + (size_t)128 * NUM_PROD,  Bs + 128 * BK);      // B1(0)
    stage_half(Ag + (size_t)128 * NUM_PROD,  As + 128 * BK);      // A1(0)
    stage_half(Ag + BK,                      As + BUF_ELEMS);     // A0(1)
    stage_half(Bg + BK,                      Bs + BUF_ELEMS);     // B0(1)
    WAITV(4);                     // tile0 landed; A0(1),B0(1) stay in flight
    __builtin_amdgcn_s_barrier();

    for (int t = 0; t < NT; ++t) {
        const u16* As_t = As + (t & 1) * BUF_ELEMS;
        const u16* Bs_t = Bs + (t & 1) * BUF_ELEMS;
        u16* As_n = As + ((t + 1) & 1) * BUF_ELEMS;
        u16* Bs_n = Bs + ((t + 1) & 1) * BUF_ELEMS;
        u16* As_c = As + (t & 1) * BUF_ELEMS;     // t+2 reuses current buffer
        u16* Bs_c = Bs + (t & 1) * BUF_ELEMS;
        const int tn = t + 1, tnn = t + 2;

        // p1: quadrant (0,0) reads A0,B0 | stage B1(t+1) into other buffer
        PHASE(0, 0,
              { if (tn < NT) stage_half(Bg + (size_t)128 * NUM_PROD + tn * BK, Bs_n + 128 * BK); },
              { })
        // p2: quadrant (0,1) reads A0,B1 | stage A1(t+1)
        PHASE(0, 1,
              { if (tn < NT) stage_half(Ag + (size_t)128 * NUM_PROD + tn * BK, As_n + 128 * BK); },
              { })
        // p3: quadrant (1,0) reads A1,B0 | stage A0(t+2) (A0(t) dead after p2)
        PHASE(1, 0,
              { if (tnn < NT) stage_half(Ag + (size_t)tnn * BK, As_c); },
              { })
        // p4: quadrant (1,1) reads A1,B1 | stage B0(t+2) (B0(t) dead after p3)
        //     boundary: guarantee tile t+1 landed, keep A0/B0(t+2) in flight
        PHASE(1, 1,
              { if (tnn < NT) stage_half(Bg + (size_t)tnn * BK, Bs_c); },
              { if (tnn < NT) { WAITV(4); } else if (tn < NT) { WAITV(0); } })
    }

    // Epilogue: C/D layout col = lane&15, row = quad*4 + reg   [m89/m91]
    float* Cb = C + (size_t)by * 256 * OUT_DIM + (size_t)bx * 256;
#pragma unroll
    for (int rh = 0; rh < 2; ++rh)
#pragma unroll
      for (int ch = 0; ch < 2; ++ch)
#pragma unroll
        for (int mt = 0; mt < 4; ++mt)
#pragma unroll
          for (int nt = 0; nt < 2; ++nt) {
            const int row0 = rh * 128 + wrow + mt * 16 + q * 4;
            const int col  = ch * 128 + wcol + nt * 16 + lr;
            float* cp = Cb + (size_t)row0 * OUT_DIM + col;
#pragma unroll
            for (int rr = 0; rr < 4; ++rr)
                cp[(size_t)rr * OUT_DIM] = acc[rh][ch][mt][nt][rr];
          }
}

// ---------------------------------------------------------------------------
extern "C" void kernel_launch(void* const* d_in, const int* in_sizes, int n_in,
                              void* d_out, int out_size, void* d_ws, size_t ws_size,
                              hipStream_t stream) {
    const float* x   = (const float*)d_in[0];
    const int*   idx = (const int*)d_in[1];
    const float* W   = (const float*)d_in[2];
    float*       out = (float*)d_out;

    const size_t wb_bytes = (size_t)OUT_DIM * NUM_PROD * 2;   // 8 MB bf16 W
    u16* Wb = (u16*)d_ws;
    u16* Q  = (u16*)((char*)d_ws + wb_bytes);

    // Largest B-chunk whose bf16 Q buffer fits in the workspace (multiple of 256).
    const size_t qcap = (ws_size > wb_bytes) ? (ws_size - wb_bytes) : 0;
    int rows = BTOT;
    while (rows > 256 && (size_t)rows * NUM_PROD * 2 > qcap) rows >>= 1;

    cast_w_kernel<<<(OUT_DIM * NUM_PROD) / (256 * 8), 256, 0, stream>>>(W, Wb);

    for (int base = 0; base < BTOT; base += rows) {
        quad_kernel<<<rows / 32, 256, 0, stream>>>(x, idx, Q, base, rows);
        dim3 g(OUT_DIM / 256, rows / 256);
        gemm256<<<g, dim3(512), 0, stream>>>(Q, Wb, out + (size_t)base * OUT_DIM);
    }
}